// Round 2
// baseline (500.112 us; speedup 1.0000x reference)
//
#include <hip/hip_runtime.h>
#include <math.h>

#define HH 128
#define WW 128
#define HW 16384
#define CIN 64
#define COUT 64
#define BATCH 8

// ---------------------------------------------------------------------------
// Kernel T: pre-transpose weights into workspace.
//   wT [kk][c][cout]  (9,64,64)  <- weight (Cout,C,3,3)
//   owT[c][k][ko]     (64,9,27)  <- offset_w (27,C,3,3)
// ---------------------------------------------------------------------------
__global__ __launch_bounds__(256) void transpose_kernel(
    const float* __restrict__ weight,
    const float* __restrict__ offset_w,
    float* __restrict__ wT,
    float* __restrict__ owT)
{
    int idx = blockIdx.x * 256 + threadIdx.x;
    if (idx < 9 * 64 * 64) {
        int kk = idx >> 12;          // /4096
        int c = (idx >> 6) & 63;
        int cout = idx & 63;
        wT[idx] = weight[(cout * 64 + c) * 9 + kk];
    }
    int j = idx - 9 * 64 * 64;
    if (j >= 0 && j < 64 * 9 * 27) {
        int c = j / 243;
        int k = (j / 27) % 9;
        int ko = j % 27;
        owT[j] = offset_w[(ko * 64 + c) * 9 + k];
    }
}

// ---------------------------------------------------------------------------
// Kernel A: 3x3 conv (C=64 -> 27), pad 1, stride 1. Produces raw offsets
// (channels 0..17) and sigmoid(mask) (channels 18..26).
// One thread = one output pixel, 27 accumulators in registers.
// XCD swizzle: image b = bid % 8 pins each image's x (4 MB) to one XCD L2.
// Software pipeline: prefetch next channel plane's 9 taps during FMAs.
// ---------------------------------------------------------------------------
__global__ __launch_bounds__(256) void offset_conv_kernel(
    const float* __restrict__ x,
    const float* __restrict__ owT,      // (64,9,27)
    const float* __restrict__ offset_b, // (27,)
    float* __restrict__ off_out,        // (B,18,HW)
    float* __restrict__ mask_out)       // (B,9,HW)
{
    int bid = blockIdx.x;
    int b = bid & 7;                    // image -> XCD (round-robin dispatch)
    int pix = ((bid >> 3) << 8) + threadIdx.x;
    int ho = pix >> 7;
    int wo = pix & 127;

    float acc[27];
#pragma unroll
    for (int ko = 0; ko < 27; ++ko) acc[ko] = offset_b[ko];

    const float* xb = x + (size_t)b * CIN * HW;

    // tap validity + clamped addresses (same for every c)
    bool okv[9];
    int tapoff[9];
#pragma unroll
    for (int ky = 0; ky < 3; ++ky) {
        int y = ho + ky - 1;
        bool yok = (unsigned)y < (unsigned)HH;
#pragma unroll
        for (int kx = 0; kx < 3; ++kx) {
            int xx = wo + kx - 1;
            bool ok = yok && ((unsigned)xx < (unsigned)WW);
            okv[ky * 3 + kx] = ok;
            int yc = min(max(y, 0), HH - 1);
            int xc2 = min(max(xx, 0), WW - 1);
            tapoff[ky * 3 + kx] = yc * WW + xc2;
        }
    }

    float v[9];
#pragma unroll
    for (int k = 0; k < 9; ++k) v[k] = okv[k] ? xb[tapoff[k]] : 0.0f;

    for (int c = 0; c < CIN; ++c) {
        // prefetch next plane
        int cn = (c + 1 < CIN) ? (c + 1) : c;
        const float* xn = xb + cn * HW;
        float vn[9];
#pragma unroll
        for (int k = 0; k < 9; ++k) vn[k] = okv[k] ? xn[tapoff[k]] : 0.0f;

        const float* wp = owT + c * 243;  // contiguous, block-uniform
#pragma unroll
        for (int k = 0; k < 9; ++k) {
#pragma unroll
            for (int ko = 0; ko < 27; ++ko) {
                acc[ko] = fmaf(v[k], wp[k * 27 + ko], acc[ko]);
            }
        }
#pragma unroll
        for (int k = 0; k < 9; ++k) v[k] = vn[k];
    }

    // channels 0..17 -> offsets; 18..26 -> sigmoid -> mask
#pragma unroll
    for (int j = 0; j < 18; ++j) {
        off_out[((size_t)b * 18 + j) * HW + pix] = acc[j];
    }
#pragma unroll
    for (int kk = 0; kk < 9; ++kk) {
        float a = acc[18 + kk];
        mask_out[((size_t)b * 9 + kk) * HW + pix] = 1.0f / (1.0f + __expf(-a));
    }
}

// ---------------------------------------------------------------------------
// Kernel B: deformable conv. One thread = one output pixel, all 64 Cout
// accumulators in registers. XCD swizzle as above. Per (kk): bilinear coords
// once; c-loop software-pipelined: prefetch 4 corners of plane c+1 while the
// 64 FMAs of plane c execute.
// ---------------------------------------------------------------------------
__global__ __launch_bounds__(256) void deform_kernel(
    const float* __restrict__ x,
    const float* __restrict__ wT,      // (9,64,64) [kk][c][cout]
    const float* __restrict__ bias,    // (64,)
    const float* __restrict__ off_in,  // (B,18,HW)
    const float* __restrict__ mask_in, // (B,9,HW)
    float* __restrict__ out)           // (B,64,HW)
{
    int bid = blockIdx.x;
    int b = bid & 7;                    // image -> XCD
    int pix = ((bid >> 3) << 8) + threadIdx.x;
    int ho = pix >> 7;
    int wo = pix & 127;

    float acc[COUT];
#pragma unroll
    for (int i = 0; i < COUT; ++i) acc[i] = bias[i];

    const float* xb = x + (size_t)b * CIN * HW;

    for (int kk = 0; kk < 9; ++kk) {
        float dy = off_in[((size_t)b * 18 + 2 * kk) * HW + pix];
        float dx = off_in[((size_t)b * 18 + 2 * kk + 1) * HW + pix];
        float m = mask_in[((size_t)b * 9 + kk) * HW + pix];

        int ky = kk / 3;
        int kx = kk - ky * 3;
        float py = dy + (float)(ky + ho - 1);
        float px = dx + (float)(kx + wo - 1);

        float y0f = floorf(py);
        float x0f = floorf(px);
        float wy = py - y0f;
        float wx = px - x0f;
        int y0 = (int)y0f;
        int x0 = (int)x0f;
        int y1 = y0 + 1;
        int x1 = x0 + 1;

        bool y0ok = (unsigned)y0 < (unsigned)HH;
        bool y1ok = (unsigned)y1 < (unsigned)HH;
        bool x0ok = (unsigned)x0 < (unsigned)WW;
        bool x1ok = (unsigned)x1 < (unsigned)WW;

        float w00 = (y0ok && x0ok) ? (1.0f - wy) * (1.0f - wx) * m : 0.0f;
        float w01 = (y0ok && x1ok) ? (1.0f - wy) * wx * m : 0.0f;
        float w10 = (y1ok && x0ok) ? wy * (1.0f - wx) * m : 0.0f;
        float w11 = (y1ok && x1ok) ? wy * wx * m : 0.0f;

        int y0c = min(max(y0, 0), HH - 1);
        int y1c = min(max(y1, 0), HH - 1);
        int x0c = min(max(x0, 0), WW - 1);
        int x1c = min(max(x1, 0), WW - 1);
        int i00 = y0c * WW + x0c;
        int i01 = y0c * WW + x1c;
        int i10 = y1c * WW + x0c;
        int i11 = y1c * WW + x1c;

        const float* wkk = wT + kk * 4096;

        // software-pipelined c-loop
        float g0 = xb[i00], g1 = xb[i01], g2 = xb[i10], g3 = xb[i11];
        for (int c = 0; c < CIN; ++c) {
            int cn = (c + 1 < CIN) ? (c + 1) : c;
            const float* xn = xb + cn * HW;
            float n0 = xn[i00];
            float n1 = xn[i01];
            float n2 = xn[i10];
            float n3 = xn[i11];

            float s = fmaf(g3, w11, fmaf(g2, w10, fmaf(g1, w01, g0 * w00)));

            const float4* wp = (const float4*)(wkk + c * 64);
#pragma unroll
            for (int q = 0; q < 16; ++q) {
                float4 w4 = wp[q];
                acc[q * 4 + 0] = fmaf(s, w4.x, acc[q * 4 + 0]);
                acc[q * 4 + 1] = fmaf(s, w4.y, acc[q * 4 + 1]);
                acc[q * 4 + 2] = fmaf(s, w4.z, acc[q * 4 + 2]);
                acc[q * 4 + 3] = fmaf(s, w4.w, acc[q * 4 + 3]);
            }
            g0 = n0; g1 = n1; g2 = n2; g3 = n3;
        }
    }

    float* ob = out + (size_t)b * COUT * HW + pix;
#pragma unroll
    for (int cout = 0; cout < COUT; ++cout) {
        ob[(size_t)cout * HW] = acc[cout];
    }
}

// ---------------------------------------------------------------------------
extern "C" void kernel_launch(void* const* d_in, const int* in_sizes, int n_in,
                              void* d_out, int out_size, void* d_ws, size_t ws_size,
                              hipStream_t stream) {
    const float* x        = (const float*)d_in[0];
    const float* weight   = (const float*)d_in[1];
    const float* bias     = (const float*)d_in[2];
    const float* offset_w = (const float*)d_in[3];
    const float* offset_b = (const float*)d_in[4];
    float* out = (float*)d_out;

    float* ws = (float*)d_ws;
    float* off_buf  = ws;                                // B*18*HW floats
    float* mask_buf = off_buf + (size_t)BATCH * 18 * HW; // B*9*HW floats
    float* wT       = mask_buf + (size_t)BATCH * 9 * HW; // 9*64*64
    float* owT      = wT + 9 * 64 * 64;                  // 64*9*27

    int n_t = 9 * 64 * 64 + 64 * 9 * 27;
    transpose_kernel<<<(n_t + 255) / 256, 256, 0, stream>>>(weight, offset_w, wT, owT);

    int n_pix_blocks = BATCH * HW / 256;  // 512
    offset_conv_kernel<<<n_pix_blocks, 256, 0, stream>>>(x, owT, offset_b, off_buf, mask_buf);
    deform_kernel<<<n_pix_blocks, 256, 0, stream>>>(x, wT, bias, off_buf, mask_buf, out);
}

// Round 3
// 361.149 us; speedup vs baseline: 1.3848x; 1.3848x over previous
//
#include <hip/hip_runtime.h>
#include <math.h>

#define HH 128
#define WW 128
#define HW 16384
#define CIN 64
#define COUT 64
#define BATCH 8

// ---------------------------------------------------------------------------
// Kernel T: pre-transpose weights into workspace.
//   wT [kk][c][cout]  (9,64,64)  <- weight (Cout,C,3,3)
//   owT[c][k][ko]     (64,9,27)  <- offset_w (27,C,3,3)
// ---------------------------------------------------------------------------
__global__ __launch_bounds__(256) void transpose_kernel(
    const float* __restrict__ weight,
    const float* __restrict__ offset_w,
    float* __restrict__ wT,
    float* __restrict__ owT)
{
    int idx = blockIdx.x * 256 + threadIdx.x;
    if (idx < 9 * 64 * 64) {
        int kk = idx >> 12;          // /4096
        int c = (idx >> 6) & 63;
        int cout = idx & 63;
        wT[idx] = weight[(cout * 64 + c) * 9 + kk];
    }
    int j = idx - 9 * 64 * 64;
    if (j >= 0 && j < 64 * 9 * 27) {
        int c = j / 243;
        int k = (j / 27) % 9;
        int ko = j % 27;
        owT[j] = offset_w[(ko * 64 + c) * 9 + k];
    }
}

// ---------------------------------------------------------------------------
// Kernel A: 3x3 conv (C=64 -> 27), pad 1, stride 1. Produces raw offsets
// (channels 0..17) and sigmoid(mask) (channels 18..26).
// One thread = one output pixel, 27 accumulators in registers.
// __launch_bounds__(256,3): 27 acc + 18 pipeline regs + temps needs ~80+
// VGPRs; default budget (~48) was spilling accumulators through AGPRs.
// ---------------------------------------------------------------------------
__global__ __launch_bounds__(256, 3) void offset_conv_kernel(
    const float* __restrict__ x,
    const float* __restrict__ owT,      // (64,9,27)
    const float* __restrict__ offset_b, // (27,)
    float* __restrict__ off_out,        // (B,18,HW)
    float* __restrict__ mask_out)       // (B,9,HW)
{
    int bid = blockIdx.x;
    int b = bid & 7;                    // image -> XCD (round-robin dispatch)
    int pix = ((bid >> 3) << 8) + threadIdx.x;
    int ho = pix >> 7;
    int wo = pix & 127;

    float acc[27];
#pragma unroll
    for (int ko = 0; ko < 27; ++ko) acc[ko] = offset_b[ko];

    const float* xb = x + (size_t)b * CIN * HW;

    // tap validity + clamped addresses (same for every c)
    bool okv[9];
    int tapoff[9];
#pragma unroll
    for (int ky = 0; ky < 3; ++ky) {
        int y = ho + ky - 1;
        bool yok = (unsigned)y < (unsigned)HH;
#pragma unroll
        for (int kx = 0; kx < 3; ++kx) {
            int xx = wo + kx - 1;
            bool ok = yok && ((unsigned)xx < (unsigned)WW);
            okv[ky * 3 + kx] = ok;
            int yc = min(max(y, 0), HH - 1);
            int xc2 = min(max(xx, 0), WW - 1);
            tapoff[ky * 3 + kx] = yc * WW + xc2;
        }
    }

    float v[9];
#pragma unroll
    for (int k = 0; k < 9; ++k) v[k] = okv[k] ? xb[tapoff[k]] : 0.0f;

    for (int c = 0; c < CIN; ++c) {
        // prefetch next plane (9 loads in flight over 243 FMAs)
        int cn = (c + 1 < CIN) ? (c + 1) : c;
        const float* xn = xb + cn * HW;
        float vn[9];
#pragma unroll
        for (int k = 0; k < 9; ++k) vn[k] = okv[k] ? xn[tapoff[k]] : 0.0f;

        const float* wp = owT + c * 243;  // contiguous, block-uniform
#pragma unroll
        for (int k = 0; k < 9; ++k) {
#pragma unroll
            for (int ko = 0; ko < 27; ++ko) {
                acc[ko] = fmaf(v[k], wp[k * 27 + ko], acc[ko]);
            }
        }
#pragma unroll
        for (int k = 0; k < 9; ++k) v[k] = vn[k];
    }

    // channels 0..17 -> offsets; 18..26 -> sigmoid -> mask
#pragma unroll
    for (int j = 0; j < 18; ++j) {
        off_out[((size_t)b * 18 + j) * HW + pix] = acc[j];
    }
#pragma unroll
    for (int kk = 0; kk < 9; ++kk) {
        float a = acc[18 + kk];
        mask_out[((size_t)b * 9 + kk) * HW + pix] = 1.0f / (1.0f + __expf(-a));
    }
}

// ---------------------------------------------------------------------------
// Kernel B: deformable conv. One thread = one output pixel, all 64 Cout
// accumulators in registers.
// __launch_bounds__(256,2): 256-VGPR budget. The grid (512 blocks = 2048
// waves) only supports 2 waves/SIMD anyway; default budget (~48 VGPR) was
// forcing the 64 accumulators through AGPR/scratch shuffles (~3 VALU per
// useful FMA, VALUBusy 27%).
// c-loop unrolled x2: 8 gather loads issued before 128 FMAs (MLP depth 8).
// ---------------------------------------------------------------------------
__global__ __launch_bounds__(256, 2) void deform_kernel(
    const float* __restrict__ x,
    const float* __restrict__ wT,      // (9,64,64) [kk][c][cout]
    const float* __restrict__ bias,    // (64,)
    const float* __restrict__ off_in,  // (B,18,HW)
    const float* __restrict__ mask_in, // (B,9,HW)
    float* __restrict__ out)           // (B,64,HW)
{
    int bid = blockIdx.x;
    int b = bid & 7;                    // image -> XCD
    int pix = ((bid >> 3) << 8) + threadIdx.x;
    int ho = pix >> 7;
    int wo = pix & 127;

    float acc[COUT];
#pragma unroll
    for (int i = 0; i < COUT; ++i) acc[i] = bias[i];

    const float* xb = x + (size_t)b * CIN * HW;

    for (int kk = 0; kk < 9; ++kk) {
        float dy = off_in[((size_t)b * 18 + 2 * kk) * HW + pix];
        float dx = off_in[((size_t)b * 18 + 2 * kk + 1) * HW + pix];
        float m = mask_in[((size_t)b * 9 + kk) * HW + pix];

        int ky = kk / 3;
        int kx = kk - ky * 3;
        float py = dy + (float)(ky + ho - 1);
        float px = dx + (float)(kx + wo - 1);

        float y0f = floorf(py);
        float x0f = floorf(px);
        float wy = py - y0f;
        float wx = px - x0f;
        int y0 = (int)y0f;
        int x0 = (int)x0f;
        int y1 = y0 + 1;
        int x1 = x0 + 1;

        bool y0ok = (unsigned)y0 < (unsigned)HH;
        bool y1ok = (unsigned)y1 < (unsigned)HH;
        bool x0ok = (unsigned)x0 < (unsigned)WW;
        bool x1ok = (unsigned)x1 < (unsigned)WW;

        float w00 = (y0ok && x0ok) ? (1.0f - wy) * (1.0f - wx) * m : 0.0f;
        float w01 = (y0ok && x1ok) ? (1.0f - wy) * wx * m : 0.0f;
        float w10 = (y1ok && x0ok) ? wy * (1.0f - wx) * m : 0.0f;
        float w11 = (y1ok && x1ok) ? wy * wx * m : 0.0f;

        int y0c = min(max(y0, 0), HH - 1);
        int y1c = min(max(y1, 0), HH - 1);
        int x0c = min(max(x0, 0), WW - 1);
        int x1c = min(max(x1, 0), WW - 1);
        int i00 = y0c * WW + x0c;
        int i01 = y0c * WW + x1c;
        int i10 = y1c * WW + x0c;
        int i11 = y1c * WW + x1c;

        const float* wkk = wT + kk * 4096;

        // software pipeline, unroll x2: corners for c and c+1 live; prefetch
        // c+2, c+3 before the 128 FMAs.
        float a0 = xb[i00], a1 = xb[i01], a2 = xb[i10], a3 = xb[i11];
        const float* xc1 = xb + HW;
        float b0 = xc1[i00], b1 = xc1[i01], b2 = xc1[i10], b3 = xc1[i11];

        for (int c = 0; c < CIN; c += 2) {
            int cn0 = (c + 2 < CIN) ? (c + 2) : c;
            int cn1 = (c + 3 < CIN) ? (c + 3) : c;
            const float* xn0 = xb + cn0 * HW;
            const float* xn1 = xb + cn1 * HW;
            float n0 = xn0[i00], n1 = xn0[i01], n2 = xn0[i10], n3 = xn0[i11];
            float p0 = xn1[i00], p1 = xn1[i01], p2 = xn1[i10], p3 = xn1[i11];

            float s0 = fmaf(a3, w11, fmaf(a2, w10, fmaf(a1, w01, a0 * w00)));
            float s1 = fmaf(b3, w11, fmaf(b2, w10, fmaf(b1, w01, b0 * w00)));

            const float4* wp0 = (const float4*)(wkk + c * 64);
            const float4* wp1 = (const float4*)(wkk + c * 64 + 64);
#pragma unroll
            for (int q = 0; q < 16; ++q) {
                float4 wa = wp0[q];
                float4 wb = wp1[q];
                acc[q * 4 + 0] = fmaf(s0, wa.x, acc[q * 4 + 0]);
                acc[q * 4 + 1] = fmaf(s0, wa.y, acc[q * 4 + 1]);
                acc[q * 4 + 2] = fmaf(s0, wa.z, acc[q * 4 + 2]);
                acc[q * 4 + 3] = fmaf(s0, wa.w, acc[q * 4 + 3]);
                acc[q * 4 + 0] = fmaf(s1, wb.x, acc[q * 4 + 0]);
                acc[q * 4 + 1] = fmaf(s1, wb.y, acc[q * 4 + 1]);
                acc[q * 4 + 2] = fmaf(s1, wb.z, acc[q * 4 + 2]);
                acc[q * 4 + 3] = fmaf(s1, wb.w, acc[q * 4 + 3]);
            }
            a0 = n0; a1 = n1; a2 = n2; a3 = n3;
            b0 = p0; b1 = p1; b2 = p2; b3 = p3;
        }
    }

    float* ob = out + (size_t)b * COUT * HW + pix;
#pragma unroll
    for (int cout = 0; cout < COUT; ++cout) {
        ob[(size_t)cout * HW] = acc[cout];
    }
}

// ---------------------------------------------------------------------------
extern "C" void kernel_launch(void* const* d_in, const int* in_sizes, int n_in,
                              void* d_out, int out_size, void* d_ws, size_t ws_size,
                              hipStream_t stream) {
    const float* x        = (const float*)d_in[0];
    const float* weight   = (const float*)d_in[1];
    const float* bias     = (const float*)d_in[2];
    const float* offset_w = (const float*)d_in[3];
    const float* offset_b = (const float*)d_in[4];
    float* out = (float*)d_out;

    float* ws = (float*)d_ws;
    float* off_buf  = ws;                                // B*18*HW floats
    float* mask_buf = off_buf + (size_t)BATCH * 18 * HW; // B*9*HW floats
    float* wT       = mask_buf + (size_t)BATCH * 9 * HW; // 9*64*64
    float* owT      = wT + 9 * 64 * 64;                  // 64*9*27

    int n_t = 9 * 64 * 64 + 64 * 9 * 27;
    transpose_kernel<<<(n_t + 255) / 256, 256, 0, stream>>>(weight, offset_w, wT, owT);

    int n_pix_blocks = BATCH * HW / 256;  // 512
    offset_conv_kernel<<<n_pix_blocks, 256, 0, stream>>>(x, owT, offset_b, off_buf, mask_buf);
    deform_kernel<<<n_pix_blocks, 256, 0, stream>>>(x, wT, bias, off_buf, mask_buf, out);
}

// Round 4
// 239.666 us; speedup vs baseline: 2.0867x; 1.5069x over previous
//
#include <hip/hip_runtime.h>
#include <hip/hip_bf16.h>
#include <math.h>

#define HH 128
#define WW 128
#define HW 16384
#define CIN 64
#define COUT 64
#define BATCH 8

typedef __attribute__((ext_vector_type(8))) short short8;
typedef __attribute__((ext_vector_type(4))) float f32x4;

union FragU { short8 v; unsigned u[4]; };

static __device__ __forceinline__ unsigned short f2bf(float f) {
    __hip_bfloat16 h = __float2bfloat16(f);
    return *(unsigned short*)&h;
}

// ---------------------------------------------------------------------------
// Prep: pack weights into MFMA A-fragment layout, bf16.
//   K ordering: k = kk*64 + c   (kk in 0..8, c in 0..63), 18 K-steps of 32.
//   A-frag for step s, lane l, elem j:  row(cout) = l&15,
//       k = s*32 + 8*(l>>4) + j        (self-consistent with B-side; any
//       hardware k-slot permutation cancels since A and B use the same map)
//   wA : (4 m-tiles, 18, 64 lanes, 8) bf16   <- weight (64,64,3,3)
//   owA: (2 m-tiles, 18, 64 lanes, 8) bf16   <- offset_w (27,64,3,3), rows>=27 zero
// ---------------------------------------------------------------------------
__global__ __launch_bounds__(256) void prep_kernel(
    const float* __restrict__ weight,
    const float* __restrict__ offset_w,
    unsigned short* __restrict__ wA,
    unsigned short* __restrict__ owA)
{
    int id = blockIdx.x * 256 + threadIdx.x;
    if (id < 4 * 18 * 64) {
        int m = id / (18 * 64);
        int s = (id / 64) % 18;
        int l = id & 63;
        int cout = m * 16 + (l & 15);
        int kbase = s * 32 + 8 * (l >> 4);
#pragma unroll
        for (int j = 0; j < 8; ++j) {
            int k = kbase + j;
            int kk = k >> 6;
            int c = k & 63;
            wA[id * 8 + j] = f2bf(weight[(cout * 64 + c) * 9 + kk]);
        }
        return;
    }
    int id2 = id - 4 * 18 * 64;
    if (id2 < 2 * 18 * 64) {
        int m = id2 / (18 * 64);
        int s = (id2 / 64) % 18;
        int l = id2 & 63;
        int cout = m * 16 + (l & 15);
        int kbase = s * 32 + 8 * (l >> 4);
#pragma unroll
        for (int j = 0; j < 8; ++j) {
            int k = kbase + j;
            int kk = k >> 6;
            int c = k & 63;
            float v = (cout < 27) ? offset_w[(cout * 64 + c) * 9 + kk] : 0.0f;
            owA[id2 * 8 + j] = f2bf(v);
        }
    }
}

// ---------------------------------------------------------------------------
// Offset conv as MFMA GEMM: M=27(pad 32), K=576, N=pixels.
// Block = 4 waves, each wave owns 16 consecutive pixels of one image row.
// Lane l: pixel = l&15, k-group g = l>>4 (8 consecutive channels per step).
// ---------------------------------------------------------------------------
__global__ __launch_bounds__(256, 4) void offset_conv_kernel(
    const float* __restrict__ x,
    const unsigned short* __restrict__ owA, // (2,18,64,8) bf16
    const float* __restrict__ offset_b,     // (27,)
    float* __restrict__ off_out,            // (B,18,HW)
    float* __restrict__ mask_out)           // (B,9,HW)
{
    int lane = threadIdx.x & 63;
    int wid = threadIdx.x >> 6;
    int bid = blockIdx.x;
    int b = bid & 7;                        // image -> XCD
    int p = ((bid >> 3) * 4 + wid) * 16 + (lane & 15);
    int ho = p >> 7, wo = p & 127;
    int g = lane >> 4;

    const float* xb = x + (size_t)b * CIN * HW;
    const short8* owAv = (const short8*)owA;

    f32x4 acc[2];
#pragma unroll
    for (int m = 0; m < 2; ++m) {
#pragma unroll
        for (int r = 0; r < 4; ++r) {
            int cout = m * 16 + g * 4 + r;
            acc[m][r] = (cout < 27) ? offset_b[cout] : 0.0f;
        }
    }

    for (int kk = 0; kk < 9; ++kk) {
        int iy = ho + (kk / 3) - 1;
        int ix = wo + (kk % 3) - 1;
        bool ok = ((unsigned)iy < (unsigned)HH) && ((unsigned)ix < (unsigned)WW);
        int iyc = min(max(iy, 0), HH - 1);
        int ixc = min(max(ix, 0), WW - 1);
        int ii = iyc * WW + ixc;

#pragma unroll
        for (int half = 0; half < 2; ++half) {
            int s = kk * 2 + half;
            const float* xp = xb + (size_t)(half * 32 + 8 * g) * HW;
            float v[8];
#pragma unroll
            for (int j = 0; j < 8; ++j) {
                v[j] = ok ? xp[(size_t)j * HW + ii] : 0.0f;
            }
            FragU bf;
#pragma unroll
            for (int jj = 0; jj < 4; ++jj) {
                float2 f2; f2.x = v[2 * jj]; f2.y = v[2 * jj + 1];
                __hip_bfloat162 h2 = __float22bfloat162_rn(f2);
                bf.u[jj] = *(unsigned*)&h2;
            }
            short8 a0 = owAv[(0 * 18 + s) * 64 + lane];
            acc[0] = __builtin_amdgcn_mfma_f32_16x16x32_bf16(a0, bf.v, acc[0], 0, 0, 0);
            short8 a1 = owAv[(1 * 18 + s) * 64 + lane];
            acc[1] = __builtin_amdgcn_mfma_f32_16x16x32_bf16(a1, bf.v, acc[1], 0, 0, 0);
        }
    }

    // D: row(cout) = g*4 + r (+16 per m-tile), col(pixel) = lane&15
#pragma unroll
    for (int m = 0; m < 2; ++m) {
#pragma unroll
        for (int r = 0; r < 4; ++r) {
            int cout = m * 16 + g * 4 + r;
            float a = acc[m][r];
            if (cout < 18) {
                off_out[((size_t)b * 18 + cout) * HW + p] = a;
            } else if (cout < 27) {
                mask_out[((size_t)b * 9 + (cout - 18)) * HW + p] =
                    1.0f / (1.0f + __expf(-a));
            }
        }
    }
}

// ---------------------------------------------------------------------------
// Deformable conv as MFMA GEMM: M=64, K=576, N=pixels.
// Per kk: one bilerp weight set per lane (its pixel); per K-step lane gathers
// 4 corners x 8 consecutive channel planes, bilerps, converts to bf16 B-frag.
// ---------------------------------------------------------------------------
__global__ __launch_bounds__(256, 4) void deform_kernel(
    const float* __restrict__ x,
    const unsigned short* __restrict__ wA, // (4,18,64,8) bf16
    const float* __restrict__ bias,        // (64,)
    const float* __restrict__ off_in,      // (B,18,HW)
    const float* __restrict__ mask_in,     // (B,9,HW)
    float* __restrict__ out)               // (B,64,HW)
{
    int lane = threadIdx.x & 63;
    int wid = threadIdx.x >> 6;
    int bid = blockIdx.x;
    int b = bid & 7;                        // image -> XCD
    int p = ((bid >> 3) * 4 + wid) * 16 + (lane & 15);
    int ho = p >> 7, wo = p & 127;
    int g = lane >> 4;

    const float* xb = x + (size_t)b * CIN * HW;
    const short8* wAv = (const short8*)wA;

    f32x4 acc[4];
#pragma unroll
    for (int m = 0; m < 4; ++m) {
        acc[m] = *(const f32x4*)(bias + m * 16 + g * 4);
    }

    for (int kk = 0; kk < 9; ++kk) {
        float dy = off_in[((size_t)b * 18 + 2 * kk) * HW + p];
        float dx = off_in[((size_t)b * 18 + 2 * kk + 1) * HW + p];
        float mm = mask_in[((size_t)b * 9 + kk) * HW + p];

        float py = dy + (float)(kk / 3 + ho - 1);
        float px = dx + (float)(kk % 3 + wo - 1);

        float y0f = floorf(py);
        float x0f = floorf(px);
        float wy = py - y0f;
        float wx = px - x0f;
        int y0 = (int)y0f;
        int x0 = (int)x0f;
        int y1 = y0 + 1;
        int x1 = x0 + 1;

        bool y0ok = (unsigned)y0 < (unsigned)HH;
        bool y1ok = (unsigned)y1 < (unsigned)HH;
        bool x0ok = (unsigned)x0 < (unsigned)WW;
        bool x1ok = (unsigned)x1 < (unsigned)WW;

        // fold mask into bilerp weights; invalid corners zeroed
        float w00 = (y0ok && x0ok) ? (1.0f - wy) * (1.0f - wx) * mm : 0.0f;
        float w01 = (y0ok && x1ok) ? (1.0f - wy) * wx * mm : 0.0f;
        float w10 = (y1ok && x0ok) ? wy * (1.0f - wx) * mm : 0.0f;
        float w11 = (y1ok && x1ok) ? wy * wx * mm : 0.0f;

        int y0c = min(max(y0, 0), HH - 1);
        int y1c = min(max(y1, 0), HH - 1);
        int x0c = min(max(x0, 0), WW - 1);
        int x1c = min(max(x1, 0), WW - 1);
        int i00 = y0c * WW + x0c;
        int i01 = y0c * WW + x1c;
        int i10 = y1c * WW + x0c;
        int i11 = y1c * WW + x1c;

#pragma unroll
        for (int half = 0; half < 2; ++half) {
            int s = kk * 2 + half;
            const float* xp = xb + (size_t)(half * 32 + 8 * g) * HW;
            float sm[8];
#pragma unroll
            for (int j = 0; j < 8; ++j) {
                const float* xc = xp + (size_t)j * HW;
                float g00 = xc[i00];
                float g01 = xc[i01];
                float g10 = xc[i10];
                float g11 = xc[i11];
                sm[j] = fmaf(g11, w11, fmaf(g10, w10, fmaf(g01, w01, g00 * w00)));
            }
            FragU bf;
#pragma unroll
            for (int jj = 0; jj < 4; ++jj) {
                float2 f2; f2.x = sm[2 * jj]; f2.y = sm[2 * jj + 1];
                __hip_bfloat162 h2 = __float22bfloat162_rn(f2);
                bf.u[jj] = *(unsigned*)&h2;
            }
#pragma unroll
            for (int m = 0; m < 4; ++m) {
                short8 a = wAv[(m * 18 + s) * 64 + lane];
                acc[m] = __builtin_amdgcn_mfma_f32_16x16x32_bf16(a, bf.v, acc[m], 0, 0, 0);
            }
        }
    }

    // D: row(cout) = m*16 + g*4 + r, col(pixel) = lane&15
#pragma unroll
    for (int m = 0; m < 4; ++m) {
#pragma unroll
        for (int r = 0; r < 4; ++r) {
            int cout = m * 16 + g * 4 + r;
            out[((size_t)b * COUT + cout) * HW + p] = acc[m][r];
        }
    }
}

// ---------------------------------------------------------------------------
extern "C" void kernel_launch(void* const* d_in, const int* in_sizes, int n_in,
                              void* d_out, int out_size, void* d_ws, size_t ws_size,
                              hipStream_t stream) {
    const float* x        = (const float*)d_in[0];
    const float* weight   = (const float*)d_in[1];
    const float* bias     = (const float*)d_in[2];
    const float* offset_w = (const float*)d_in[3];
    const float* offset_b = (const float*)d_in[4];
    float* out = (float*)d_out;

    float* ws = (float*)d_ws;
    float* off_buf  = ws;                                // B*18*HW floats
    float* mask_buf = off_buf + (size_t)BATCH * 18 * HW; // B*9*HW floats
    unsigned short* wA  = (unsigned short*)(mask_buf + (size_t)BATCH * 9 * HW); // 4*18*64*8 bf16
    unsigned short* owA = wA + 4 * 18 * 64 * 8;                                  // 2*18*64*8 bf16

    // prep: 4608 + 2304 = 6912 threads
    prep_kernel<<<27, 256, 0, stream>>>(weight, offset_w, wA, owA);

    int n_blocks = BATCH * HW / 64;  // 2048 (4 waves x 16 pixels per block)
    offset_conv_kernel<<<n_blocks, 256, 0, stream>>>(x, owA, offset_b, off_buf, mask_buf);
    deform_kernel<<<n_blocks, 256, 0, stream>>>(x, wA, bias, off_buf, mask_buf, out);
}

// Round 5
// 126.764 us; speedup vs baseline: 3.9452x; 1.8906x over previous
//
#include <hip/hip_runtime.h>
#include <hip/hip_bf16.h>
#include <math.h>

#define HH 128
#define WW 128
#define HW 16384
#define CIN 64
#define COUT 64
#define BATCH 8

typedef __attribute__((ext_vector_type(8))) short short8;
typedef __attribute__((ext_vector_type(4))) float f32x4;
typedef __attribute__((ext_vector_type(4))) unsigned int u32x4;

union FragU { short8 v; unsigned int u[4]; u32x4 q; };

static __device__ __forceinline__ unsigned short f2bf(float f) {
    __hip_bfloat16 h = __float2bfloat16(f);
    return *(unsigned short*)&h;
}
static __device__ __forceinline__ float bf_lo(unsigned int r) {  // even channel
    return __uint_as_float(r << 16);
}
static __device__ __forceinline__ float bf_hi(unsigned int r) {  // odd channel
    return __uint_as_float(r & 0xffff0000u);
}

// ---------------------------------------------------------------------------
// Prep: pack weights into MFMA A-fragment layout, bf16 (identical to round 4;
// k = s*32 + 8*(l>>4) + j, c = k&63, kk = k>>6 — matches B-side generation).
// ---------------------------------------------------------------------------
__global__ __launch_bounds__(256) void prep_kernel(
    const float* __restrict__ weight,
    const float* __restrict__ offset_w,
    unsigned short* __restrict__ wA,
    unsigned short* __restrict__ owA)
{
    int id = blockIdx.x * 256 + threadIdx.x;
    if (id < 4 * 18 * 64) {
        int m = id / (18 * 64);
        int s = (id / 64) % 18;
        int l = id & 63;
        int cout = m * 16 + (l & 15);
        int kbase = s * 32 + 8 * (l >> 4);
#pragma unroll
        for (int j = 0; j < 8; ++j) {
            int k = kbase + j;
            int kk = k >> 6;
            int c = k & 63;
            wA[id * 8 + j] = f2bf(weight[(cout * 64 + c) * 9 + kk]);
        }
        return;
    }
    int id2 = id - 4 * 18 * 64;
    if (id2 < 2 * 18 * 64) {
        int m = id2 / (18 * 64);
        int s = (id2 / 64) % 18;
        int l = id2 & 63;
        int cout = m * 16 + (l & 15);
        int kbase = s * 32 + 8 * (l >> 4);
#pragma unroll
        for (int j = 0; j < 8; ++j) {
            int k = kbase + j;
            int kk = k >> 6;
            int c = k & 63;
            float v = (cout < 27) ? offset_w[(cout * 64 + c) * 9 + kk] : 0.0f;
            owA[id2 * 8 + j] = f2bf(v);
        }
    }
}

// ---------------------------------------------------------------------------
// Transform: x NCHW fp32 -> xT NHWC bf16 (stored as u32 channel-pairs).
// Block = 64 px x 64 ch tile via LDS ([64][33] u32, pad kills bank conflicts).
// Read coalesced per channel plane; write 2x dwordx4 per pixel-quarter.
// ---------------------------------------------------------------------------
__global__ __launch_bounds__(256) void transform_kernel(
    const float* __restrict__ x,
    unsigned int* __restrict__ xT)
{
    __shared__ unsigned int lds[64][33];
    int bid = blockIdx.x;
    int b = bid & 7;                        // image -> XCD
    int pix0 = (bid >> 3) << 6;
    int t = threadIdx.x;
    int px = t & 63;
    int cp0 = (t >> 6) * 8;

    const float* xb = x + (size_t)b * CIN * HW + pix0 + px;
#pragma unroll
    for (int it = 0; it < 8; ++it) {
        int cpair = cp0 + it;
        float2 f2;
        f2.x = xb[(size_t)(2 * cpair) * HW];
        f2.y = xb[(size_t)(2 * cpair + 1) * HW];
        __hip_bfloat162 h2 = __float22bfloat162_rn(f2);
        lds[px][cpair] = *(unsigned int*)&h2;
    }
    __syncthreads();

    int wpx = t >> 2, q = t & 3;
    unsigned int* dst = xT + ((size_t)b * HW + pix0 + wpx) * 32 + q * 8;
    u32x4 a, c;
#pragma unroll
    for (int j = 0; j < 4; ++j) a[j] = lds[wpx][q * 8 + j];
#pragma unroll
    for (int j = 0; j < 4; ++j) c[j] = lds[wpx][q * 8 + 4 + j];
    *(u32x4*)dst = a;
    *(u32x4*)(dst + 4) = c;
}

// ---------------------------------------------------------------------------
// Offset conv as MFMA GEMM on NHWC bf16: the static tap value IS the
// B-fragment — one dwordx4 + 4 cndmask per K-step, no bilerp, no repack.
// ---------------------------------------------------------------------------
__global__ __launch_bounds__(256, 4) void offset_conv_kernel(
    const unsigned int* __restrict__ xT,    // NHWC bf16
    const unsigned short* __restrict__ owA, // (2,18,64,8) bf16
    const float* __restrict__ offset_b,     // (27,)
    float* __restrict__ off_out,            // (B,18,HW)
    float* __restrict__ mask_out)           // (B,9,HW)
{
    int lane = threadIdx.x & 63;
    int wid = threadIdx.x >> 6;
    int bid = blockIdx.x;
    int b = bid & 7;                        // image -> XCD
    int p = ((bid >> 3) * 4 + wid) * 16 + (lane & 15);
    int ho = p >> 7, wo = p & 127;
    int g = lane >> 4;

    const u32x4* xbv = (const u32x4*)(xT + (size_t)b * HW * 32);
    const short8* owAv = (const short8*)owA;

    f32x4 acc[2];
#pragma unroll
    for (int m = 0; m < 2; ++m) {
#pragma unroll
        for (int r = 0; r < 4; ++r) {
            int cout = m * 16 + g * 4 + r;
            acc[m][r] = (cout < 27) ? offset_b[cout] : 0.0f;
        }
    }

    for (int kk = 0; kk < 9; ++kk) {
        int iy = ho + (kk / 3) - 1;
        int ix = wo + (kk % 3) - 1;
        bool ok = ((unsigned)iy < (unsigned)HH) && ((unsigned)ix < (unsigned)WW);
        int iyc = min(max(iy, 0), HH - 1);
        int ixc = min(max(ix, 0), WW - 1);
        const u32x4* pp = xbv + (size_t)(iyc * WW + ixc) * 8 + g;

#pragma unroll
        for (int hf = 0; hf < 2; ++hf) {
            int s = kk * 2 + hf;
            u32x4 raw = pp[hf * 4];
            FragU bf;
#pragma unroll
            for (int j = 0; j < 4; ++j) bf.u[j] = ok ? raw[j] : 0u;

            short8 a0 = owAv[(0 * 18 + s) * 64 + lane];
            acc[0] = __builtin_amdgcn_mfma_f32_16x16x32_bf16(a0, bf.v, acc[0], 0, 0, 0);
            short8 a1 = owAv[(1 * 18 + s) * 64 + lane];
            acc[1] = __builtin_amdgcn_mfma_f32_16x16x32_bf16(a1, bf.v, acc[1], 0, 0, 0);
        }
    }

#pragma unroll
    for (int m = 0; m < 2; ++m) {
#pragma unroll
        for (int r = 0; r < 4; ++r) {
            int cout = m * 16 + g * 4 + r;
            float a = acc[m][r];
            if (cout < 18) {
                off_out[((size_t)b * 18 + cout) * HW + p] = a;
            } else if (cout < 27) {
                mask_out[((size_t)b * 9 + (cout - 18)) * HW + p] =
                    1.0f / (1.0f + __expf(-a));
            }
        }
    }
}

// ---------------------------------------------------------------------------
// Deformable conv as MFMA GEMM on NHWC bf16. Per K-step: 4 corner dwordx4
// loads (dense 64B lines), unpack bf16->f32, bilerp, repack -> B-frag,
// 4 MFMAs. 72 VMEM + 72 MFMA instructions per wave total.
// ---------------------------------------------------------------------------
__global__ __launch_bounds__(256, 4) void deform_kernel(
    const unsigned int* __restrict__ xT,   // NHWC bf16
    const unsigned short* __restrict__ wA, // (4,18,64,8) bf16
    const float* __restrict__ bias,        // (64,)
    const float* __restrict__ off_in,      // (B,18,HW)
    const float* __restrict__ mask_in,     // (B,9,HW)
    float* __restrict__ out)               // (B,64,HW)
{
    int lane = threadIdx.x & 63;
    int wid = threadIdx.x >> 6;
    int bid = blockIdx.x;
    int b = bid & 7;                        // image -> XCD
    int p = ((bid >> 3) * 4 + wid) * 16 + (lane & 15);
    int ho = p >> 7, wo = p & 127;
    int g = lane >> 4;

    const u32x4* xbv = (const u32x4*)(xT + (size_t)b * HW * 32);
    const short8* wAv = (const short8*)wA;

    f32x4 acc[4];
#pragma unroll
    for (int m = 0; m < 4; ++m) {
        acc[m] = *(const f32x4*)(bias + m * 16 + g * 4);
    }

    for (int kk = 0; kk < 9; ++kk) {
        float dy = off_in[((size_t)b * 18 + 2 * kk) * HW + p];
        float dx = off_in[((size_t)b * 18 + 2 * kk + 1) * HW + p];
        float mm = mask_in[((size_t)b * 9 + kk) * HW + p];

        float py = dy + (float)(kk / 3 + ho - 1);
        float px = dx + (float)(kk % 3 + wo - 1);

        float y0f = floorf(py);
        float x0f = floorf(px);
        float wy = py - y0f;
        float wx = px - x0f;
        int y0 = (int)y0f;
        int x0 = (int)x0f;
        int y1 = y0 + 1;
        int x1 = x0 + 1;

        bool y0ok = (unsigned)y0 < (unsigned)HH;
        bool y1ok = (unsigned)y1 < (unsigned)HH;
        bool x0ok = (unsigned)x0 < (unsigned)WW;
        bool x1ok = (unsigned)x1 < (unsigned)WW;

        float w00 = (y0ok && x0ok) ? (1.0f - wy) * (1.0f - wx) * mm : 0.0f;
        float w01 = (y0ok && x1ok) ? (1.0f - wy) * wx * mm : 0.0f;
        float w10 = (y1ok && x0ok) ? wy * (1.0f - wx) * mm : 0.0f;
        float w11 = (y1ok && x1ok) ? wy * wx * mm : 0.0f;

        int y0c = min(max(y0, 0), HH - 1);
        int y1c = min(max(y1, 0), HH - 1);
        int x0c = min(max(x0, 0), WW - 1);
        int x1c = min(max(x1, 0), WW - 1);

        const u32x4* p00 = xbv + (size_t)(y0c * WW + x0c) * 8 + g;
        const u32x4* p01 = xbv + (size_t)(y0c * WW + x1c) * 8 + g;
        const u32x4* p10 = xbv + (size_t)(y1c * WW + x0c) * 8 + g;
        const u32x4* p11 = xbv + (size_t)(y1c * WW + x1c) * 8 + g;

#pragma unroll
        for (int hf = 0; hf < 2; ++hf) {
            int s = kk * 2 + hf;
            u32x4 r00 = p00[hf * 4];
            u32x4 r01 = p01[hf * 4];
            u32x4 r10 = p10[hf * 4];
            u32x4 r11 = p11[hf * 4];

            FragU bf;
#pragma unroll
            for (int d = 0; d < 4; ++d) {
                float se = fmaf(bf_lo(r11[d]), w11,
                           fmaf(bf_lo(r10[d]), w10,
                           fmaf(bf_lo(r01[d]), w01, bf_lo(r00[d]) * w00)));
                float so = fmaf(bf_hi(r11[d]), w11,
                           fmaf(bf_hi(r10[d]), w10,
                           fmaf(bf_hi(r01[d]), w01, bf_hi(r00[d]) * w00)));
                float2 f2; f2.x = se; f2.y = so;
                __hip_bfloat162 h2 = __float22bfloat162_rn(f2);
                bf.u[d] = *(unsigned int*)&h2;
            }
#pragma unroll
            for (int m = 0; m < 4; ++m) {
                short8 a = wAv[(m * 18 + s) * 64 + lane];
                acc[m] = __builtin_amdgcn_mfma_f32_16x16x32_bf16(a, bf.v, acc[m], 0, 0, 0);
            }
        }
    }

#pragma unroll
    for (int m = 0; m < 4; ++m) {
#pragma unroll
        for (int r = 0; r < 4; ++r) {
            int cout = m * 16 + g * 4 + r;
            out[((size_t)b * COUT + cout) * HW + p] = acc[m][r];
        }
    }
}

// ---------------------------------------------------------------------------
extern "C" void kernel_launch(void* const* d_in, const int* in_sizes, int n_in,
                              void* d_out, int out_size, void* d_ws, size_t ws_size,
                              hipStream_t stream) {
    const float* x        = (const float*)d_in[0];
    const float* weight   = (const float*)d_in[1];
    const float* bias     = (const float*)d_in[2];
    const float* offset_w = (const float*)d_in[3];
    const float* offset_b = (const float*)d_in[4];
    float* out = (float*)d_out;

    float* ws = (float*)d_ws;
    float* off_buf  = ws;                                // B*18*HW f32
    float* mask_buf = off_buf + (size_t)BATCH * 18 * HW; // B*9*HW f32
    unsigned short* wA  = (unsigned short*)(mask_buf + (size_t)BATCH * 9 * HW); // 4*18*64*8
    unsigned short* owA = wA + 4 * 18 * 64 * 8;                                  // 2*18*64*8
    unsigned int* xT    = (unsigned int*)(owA + 2 * 18 * 64 * 8);               // B*HW*32 u32

    prep_kernel<<<27, 256, 0, stream>>>(weight, offset_w, wA, owA);

    int n_tiles = BATCH * HW / 64;   // 2048
    transform_kernel<<<n_tiles, 256, 0, stream>>>(x, xT);

    int n_blocks = BATCH * HW / 64;  // 2048 (4 waves x 16 px)
    offset_conv_kernel<<<n_blocks, 256, 0, stream>>>(xT, owA, offset_b, off_buf, mask_buf);
    deform_kernel<<<n_blocks, 256, 0, stream>>>(xT, wA, bias, off_buf, mask_buf, out);
}

// Round 6
// 104.160 us; speedup vs baseline: 4.8014x; 1.2170x over previous
//
#include <hip/hip_runtime.h>
#include <hip/hip_bf16.h>
#include <math.h>

#define HH 128
#define WW 128
#define HW 16384
#define BATCH 8

typedef __attribute__((ext_vector_type(8))) short short8;
typedef __attribute__((ext_vector_type(4))) float f32x4;
typedef __attribute__((ext_vector_type(4))) unsigned int u32x4;

union FragU { short8 v; unsigned int u[4]; u32x4 q; };

static __device__ __forceinline__ unsigned short f2bf(float f) {
    __hip_bfloat16 h = __float2bfloat16(f);
    return *(unsigned short*)&h;
}
static __device__ __forceinline__ float bf_lo(unsigned int r) {
    return __uint_as_float(r << 16);
}
static __device__ __forceinline__ float bf_hi(unsigned int r) {
    return __uint_as_float(r & 0xffff0000u);
}

// ---------------------------------------------------------------------------
// Prep: pack weights into MFMA A-fragment layout, bf16.
// k = s*32 + 8*(l>>4) + j ; c = k&63 ; kk = k>>6  (matches B-side generation)
//   wA : (4,18,64,8) bf16  <- weight (64,64,3,3)
//   owA: (2,18,64,8) bf16  <- offset_w (27,64,3,3), rows>=27 zero
// ---------------------------------------------------------------------------
__global__ __launch_bounds__(256) void prep_kernel(
    const float* __restrict__ weight,
    const float* __restrict__ offset_w,
    unsigned short* __restrict__ wA,
    unsigned short* __restrict__ owA)
{
    int id = blockIdx.x * 256 + threadIdx.x;
    if (id < 4 * 18 * 64) {
        int m = id / (18 * 64);
        int s = (id / 64) % 18;
        int l = id & 63;
        int cout = m * 16 + (l & 15);
        int kbase = s * 32 + 8 * (l >> 4);
#pragma unroll
        for (int j = 0; j < 8; ++j) {
            int k = kbase + j;
            int kk = k >> 6;
            int c = k & 63;
            wA[id * 8 + j] = f2bf(weight[(cout * 64 + c) * 9 + kk]);
        }
        return;
    }
    int id2 = id - 4 * 18 * 64;
    if (id2 < 2 * 18 * 64) {
        int m = id2 / (18 * 64);
        int s = (id2 / 64) % 18;
        int l = id2 & 63;
        int cout = m * 16 + (l & 15);
        int kbase = s * 32 + 8 * (l >> 4);
#pragma unroll
        for (int j = 0; j < 8; ++j) {
            int k = kbase + j;
            int kk = k >> 6;
            int c = k & 63;
            float v = (cout < 27) ? offset_w[(cout * 64 + c) * 9 + kk] : 0.0f;
            owA[id2 * 8 + j] = f2bf(v);
        }
    }
}

// ---------------------------------------------------------------------------
// Transform: x NCHW fp32 -> xT NHWC bf16 (u32 channel-pairs), LDS-tiled.
// ---------------------------------------------------------------------------
__global__ __launch_bounds__(256) void transform_kernel(
    const float* __restrict__ x,
    unsigned int* __restrict__ xT)
{
    __shared__ unsigned int lds[64][33];
    int bid = blockIdx.x;
    int b = bid & 7;                        // image -> XCD
    int pix0 = (bid >> 3) << 6;
    int t = threadIdx.x;
    int px = t & 63;
    int cp0 = (t >> 6) * 8;

    const float* xb = x + (size_t)b * 64 * HW + pix0 + px;
#pragma unroll
    for (int it = 0; it < 8; ++it) {
        int cpair = cp0 + it;
        float2 f2;
        f2.x = xb[(size_t)(2 * cpair) * HW];
        f2.y = xb[(size_t)(2 * cpair + 1) * HW];
        __hip_bfloat162 h2 = __float22bfloat162_rn(f2);
        lds[px][cpair] = *(unsigned int*)&h2;
    }
    __syncthreads();

    int wpx = t >> 2, q = t & 3;
    unsigned int* dst = xT + ((size_t)b * HW + pix0 + wpx) * 32 + q * 8;
    u32x4 a, c;
#pragma unroll
    for (int j = 0; j < 4; ++j) a[j] = lds[wpx][q * 8 + j];
#pragma unroll
    for (int j = 0; j < 4; ++j) c[j] = lds[wpx][q * 8 + 4 + j];
    *(u32x4*)dst = a;
    *(u32x4*)(dst + 4) = c;
}

// ---------------------------------------------------------------------------
// Fused kernel: phase 1 = offset conv (MFMA, M=27) -> offsets/masks stay on
// chip (per-wave LDS redistribute); phase 2 = deformable conv (MFMA, M=64).
// A-fragments are staged per-kk into LDS once per BLOCK (global->reg early,
// ds_write late, 2 barriers/kk) so the MFMA loop reads A via the DS pipe
// instead of re-streaming 72KB per WAVE through the TA.
// Block = 4 waves x 16 px; lane: pixel q=l&15, channel-group g=l>>4.
// ---------------------------------------------------------------------------
__global__ __launch_bounds__(256, 4) void fused_kernel(
    const unsigned int* __restrict__ xT,    // NHWC bf16
    const unsigned short* __restrict__ wA,  // (4,18,64,8) bf16
    const unsigned short* __restrict__ owA, // (2,18,64,8) bf16
    const float* __restrict__ bias,         // (64,)
    const float* __restrict__ offset_b,     // (27,)
    float* __restrict__ out)                // (B,64,HW) f32
{
    __shared__ __align__(16) unsigned int stage[2048];  // 8KB A-frag staging
    __shared__ float red[4][27][16];                    // per-wave off/mask

    int t = threadIdx.x;
    int lane = t & 63;
    int wid = t >> 6;
    int bid = blockIdx.x;
    int b = bid & 7;                        // image -> XCD
    int p = ((bid >> 3) * 4 + wid) * 16 + (lane & 15);
    int ho = p >> 7, wo = p & 127;
    int g = lane >> 4;
    int q = lane & 15;

    const u32x4* xbv = (const u32x4*)(xT + (size_t)b * HW * 32);

    // ================= phase 1: offset conv =================
    f32x4 acc1[2];
#pragma unroll
    for (int m = 0; m < 2; ++m) {
#pragma unroll
        for (int r = 0; r < 4; ++r) {
            int cout = m * 16 + g * 4 + r;
            acc1[m][r] = (cout < 27) ? offset_b[cout] : 0.0f;
        }
    }

    // staging roles: phase1 4KB/kk -> 16B/thread ; phase2 8KB/kk -> 32B/thread
    int m1 = t >> 7, j1 = t & 127;
    int m2 = t >> 6, j2 = t & 63;

    u32x4 tA = *(const u32x4*)((const char*)owA + (m1 * 18 + 0) * 1024 + j1 * 16);
    *(u32x4*)&stage[m1 * 512 + j1 * 4] = tA;

    for (int kk = 0; kk < 9; ++kk) {
        __syncthreads();                    // staged A visible
        if (kk < 8)
            tA = *(const u32x4*)((const char*)owA + (m1 * 18 + 2 * (kk + 1)) * 1024 + j1 * 16);

        int iy = ho + (kk / 3) - 1;
        int ix = wo + (kk % 3) - 1;
        bool ok = ((unsigned)iy < (unsigned)HH) && ((unsigned)ix < (unsigned)WW);
        int iyc = min(max(iy, 0), HH - 1);
        int ixc = min(max(ix, 0), WW - 1);
        const u32x4* pp = xbv + (size_t)(iyc * WW + ixc) * 8 + g;
        u32x4 tap0 = pp[0];
        u32x4 tap1 = pp[4];

#pragma unroll
        for (int hf = 0; hf < 2; ++hf) {
            u32x4 raw = hf ? tap1 : tap0;
            FragU bf;
#pragma unroll
            for (int j = 0; j < 4; ++j) bf.u[j] = ok ? raw[j] : 0u;
#pragma unroll
            for (int m = 0; m < 2; ++m) {
                FragU af;
                af.q = *(const u32x4*)&stage[m * 512 + hf * 256 + lane * 4];
                acc1[m] = __builtin_amdgcn_mfma_f32_16x16x32_bf16(af.v, bf.v, acc1[m], 0, 0, 0);
            }
        }
        __syncthreads();                    // A reads done
        if (kk < 8)
            *(u32x4*)&stage[m1 * 512 + j1 * 4] = tA;
    }

    // redistribute: lane holds cout=m*16+g*4+r for pixel q -> red[wid][cout][q]
#pragma unroll
    for (int m = 0; m < 2; ++m) {
#pragma unroll
        for (int r = 0; r < 4; ++r) {
            int cout = m * 16 + g * 4 + r;
            if (cout < 27) {
                float a = acc1[m][r];
                if (cout >= 18) a = 1.0f / (1.0f + __expf(-a));
                red[wid][cout][q] = a;
            }
        }
    }

    // ================= phase 2: deformable conv =================
    f32x4 acc[4];
#pragma unroll
    for (int m = 0; m < 4; ++m) {
        acc[m] = *(const f32x4*)(bias + m * 16 + g * 4);
    }

    u32x4 tW0 = *(const u32x4*)((const char*)wA + (m2 * 18) * 1024 + j2 * 32);
    u32x4 tW1 = *(const u32x4*)((const char*)wA + (m2 * 18) * 1024 + j2 * 32 + 16);
    __syncthreads();                        // phase-1 stage reads + red writes done
    *(u32x4*)&stage[m2 * 512 + j2 * 8] = tW0;
    *(u32x4*)&stage[m2 * 512 + j2 * 8 + 4] = tW1;

    for (int kk = 0; kk < 9; ++kk) {
        __syncthreads();                    // staged A visible
        if (kk < 8) {
            tW0 = *(const u32x4*)((const char*)wA + (m2 * 18 + 2 * (kk + 1)) * 1024 + j2 * 32);
            tW1 = *(const u32x4*)((const char*)wA + (m2 * 18 + 2 * (kk + 1)) * 1024 + j2 * 32 + 16);
        }

        float dy = red[wid][2 * kk][q];
        float dx = red[wid][2 * kk + 1][q];
        float mm = red[wid][18 + kk][q];

        float py = dy + (float)(kk / 3 + ho - 1);
        float px = dx + (float)(kk % 3 + wo - 1);

        float y0f = floorf(py);
        float x0f = floorf(px);
        float wy = py - y0f;
        float wx = px - x0f;
        int y0 = (int)y0f;
        int x0 = (int)x0f;
        int y1 = y0 + 1;
        int x1 = x0 + 1;

        bool y0ok = (unsigned)y0 < (unsigned)HH;
        bool y1ok = (unsigned)y1 < (unsigned)HH;
        bool x0ok = (unsigned)x0 < (unsigned)WW;
        bool x1ok = (unsigned)x1 < (unsigned)WW;

        float w00 = (y0ok && x0ok) ? (1.0f - wy) * (1.0f - wx) * mm : 0.0f;
        float w01 = (y0ok && x1ok) ? (1.0f - wy) * wx * mm : 0.0f;
        float w10 = (y1ok && x0ok) ? wy * (1.0f - wx) * mm : 0.0f;
        float w11 = (y1ok && x1ok) ? wy * wx * mm : 0.0f;

        int y0c = min(max(y0, 0), HH - 1);
        int y1c = min(max(y1, 0), HH - 1);
        int x0c = min(max(x0, 0), WW - 1);
        int x1c = min(max(x1, 0), WW - 1);

        const u32x4* p00 = xbv + (size_t)(y0c * WW + x0c) * 8 + g;
        const u32x4* p01 = xbv + (size_t)(y0c * WW + x1c) * 8 + g;
        const u32x4* p10 = xbv + (size_t)(y1c * WW + x0c) * 8 + g;
        const u32x4* p11 = xbv + (size_t)(y1c * WW + x1c) * 8 + g;

#pragma unroll
        for (int hf = 0; hf < 2; ++hf) {
            u32x4 r00 = p00[hf * 4];
            u32x4 r01 = p01[hf * 4];
            u32x4 r10 = p10[hf * 4];
            u32x4 r11 = p11[hf * 4];

            FragU bf;
#pragma unroll
            for (int d = 0; d < 4; ++d) {
                float se = fmaf(bf_lo(r11[d]), w11,
                           fmaf(bf_lo(r10[d]), w10,
                           fmaf(bf_lo(r01[d]), w01, bf_lo(r00[d]) * w00)));
                float so = fmaf(bf_hi(r11[d]), w11,
                           fmaf(bf_hi(r10[d]), w10,
                           fmaf(bf_hi(r01[d]), w01, bf_hi(r00[d]) * w00)));
                float2 f2; f2.x = se; f2.y = so;
                __hip_bfloat162 h2 = __float22bfloat162_rn(f2);
                bf.u[d] = *(unsigned int*)&h2;
            }
#pragma unroll
            for (int m = 0; m < 4; ++m) {
                FragU af;
                af.q = *(const u32x4*)&stage[m * 512 + hf * 256 + lane * 4];
                acc[m] = __builtin_amdgcn_mfma_f32_16x16x32_bf16(af.v, bf.v, acc[m], 0, 0, 0);
            }
        }
        __syncthreads();                    // A reads done
        if (kk < 8) {
            *(u32x4*)&stage[m2 * 512 + j2 * 8] = tW0;
            *(u32x4*)&stage[m2 * 512 + j2 * 8 + 4] = tW1;
        }
    }

    // D: row(cout) = m*16 + g*4 + r, col(pixel) = lane&15
#pragma unroll
    for (int m = 0; m < 4; ++m) {
#pragma unroll
        for (int r = 0; r < 4; ++r) {
            int cout = m * 16 + g * 4 + r;
            out[((size_t)b * 64 + cout) * HW + p] = acc[m][r];
        }
    }
}

// ---------------------------------------------------------------------------
extern "C" void kernel_launch(void* const* d_in, const int* in_sizes, int n_in,
                              void* d_out, int out_size, void* d_ws, size_t ws_size,
                              hipStream_t stream) {
    const float* x        = (const float*)d_in[0];
    const float* weight   = (const float*)d_in[1];
    const float* bias     = (const float*)d_in[2];
    const float* offset_w = (const float*)d_in[3];
    const float* offset_b = (const float*)d_in[4];
    float* out = (float*)d_out;

    unsigned int* xT = (unsigned int*)d_ws;                        // B*HW*32 u32 = 16MB
    unsigned short* wA  = (unsigned short*)(xT + (size_t)BATCH * HW * 32); // 4*18*64*8
    unsigned short* owA = wA + 4 * 18 * 64 * 8;                            // 2*18*64*8

    prep_kernel<<<27, 256, 0, stream>>>(weight, offset_w, wA, owA);

    int n_tiles = BATCH * HW / 64;   // 2048
    transform_kernel<<<n_tiles, 256, 0, stream>>>(x, xT);

    int n_blocks = BATCH * HW / 64;  // 2048 (4 waves x 16 px)
    fused_kernel<<<n_blocks, 256, 0, stream>>>(xT, wA, owA, bias, offset_b, out);
}